// Round 10
// baseline (319.357 us; speedup 1.0000x reference)
//
#include <hip/hip_runtime.h>

#define Bn 8
#define Ln 128
#define Hn 768
#define Pn 16
#define Dn 102
#define EPSF 1e-8f
#define NINF -1e30f

__device__ __forceinline__ float wred_sum(float v){
#pragma unroll
  for(int o=32;o>=1;o>>=1) v += __shfl_xor(v,o);
  return v;
}
__device__ __forceinline__ float wred_max(float v){
#pragma unroll
  for(int o=32;o>=1;o>>=1) v = fmaxf(v,__shfl_xor(v,o));
  return v;
}
// sum over the 4 hq-quarters in the p-in-lane layout (lane = p + 16*hq)
__device__ __forceinline__ float qred_sum(float v){
  v += __shfl_xor(v,16);
  v += __shfl_xor(v,32);
  return v;
}

// ---- workspace layout (float element offsets; total ~12.3 MB) ----
constexpr size_t SZ_MAT   = (size_t)Bn*Ln*Hn;              // 786432
constexpr size_t OFF_C1F  = 0;
constexpr size_t OFF_C2F  = OFF_C1F + SZ_MAT;
constexpr size_t OFF_COS  = OFF_C2F + SZ_MAT;              // B*L*L
constexpr size_t OFF_N1   = OFF_COS + (size_t)Bn*Ln*Ln;    // B*L
constexpr size_t OFF_N2   = OFF_N1 + (size_t)Bn*Ln;
constexpr size_t OFF_WN   = OFF_N2 + (size_t)Bn*Ln;        // 2*5*B*P*L
constexpr size_t OFF_W2T  = OFF_WN + (size_t)2*5*Bn*Pn*Ln; // 5*H*P [X][h][p]
constexpr size_t OFF_MVMAX  = OFF_W2T + (size_t)5*Hn*Pn;   // 2*B*L*P (side0 used)
constexpr size_t OFF_MVMEAN = OFF_MVMAX + (size_t)2*Bn*Ln*Pn;
constexpr size_t OFF_PART   = OFF_MVMEAN + (size_t)2*Bn*Ln*Pn; // B*L*P*32*2
constexpr size_t OFF_LENS   = OFF_PART + (size_t)Bn*Ln*Pn*32*2; // 32 ints

__device__ __forceinline__ size_t wnIdx(int side,int X,int b,int p,int i){
  return ((((size_t)side*5 + X)*Bn + b)*Pn + p)*Ln + i;
}

// ---------------- k_prep: lengths + squared-weight tables ----------------
__global__ __launch_bounds__(256) void k_prep(
    const float* __restrict__ m1, const float* __restrict__ m2,
    const float* __restrict__ wff, const float* __restrict__ wfb,
    const float* __restrict__ wmp, const float* __restrict__ watt,
    const float* __restrict__ wmatt,
    float* __restrict__ W2T, int* __restrict__ lens){
  int t = threadIdx.x;
  if(blockIdx.x < 8){
    int b = blockIdx.x;
    __shared__ int cnt[2];
    if(t<2) cnt[t]=0;
    __syncthreads();
    if(t<Ln){
      if(m1[b*Ln+t]>0.5f) atomicAdd(&cnt[0],1);
      if(m2[b*Ln+t]>0.5f) atomicAdd(&cnt[1],1);
    }
    __syncthreads();
    if(t==0){
      lens[b]=cnt[0]; lens[8+b]=cnt[1];
      lens[16+b]=max(cnt[0]-1,0); lens[24+b]=max(cnt[1]-1,0);
    }
  } else {
    int idx = (blockIdx.x-8)*256 + t;     // < 5*768*16 = 61440
    const float* srcs[5] = {wff,wfb,wmp,watt,wmatt};
    int X = idx/(Pn*Hn);
    int r = idx%(Pn*Hn);
    int h = r/Pn, p = r%Pn;
    float w = srcs[X][p*Hn+h];
    W2T[idx] = w*w;                        // layout [X][h][p]
  }
}

// ---------------- k_rows: masked rows + norms + weighted norms ----------------
__global__ __launch_bounds__(256) void k_rows(
    const float* __restrict__ ctx1, const float* __restrict__ m1,
    const float* __restrict__ ctx2, const float* __restrict__ m2,
    const float* __restrict__ W2T,
    float* __restrict__ c1f, float* __restrict__ c2f,
    float* __restrict__ n1, float* __restrict__ n2, float* __restrict__ wn){
  int i = blockIdx.x, b = blockIdx.y, side = blockIdx.z;
  const float* ctx = side? ctx2 : ctx1;
  const float* msk = side? m2 : m1;
  float* dst = side? c2f : c1f;
  float* nD  = side? n2 : n1;
  int t = threadIdx.x, w=t>>6, l=t&63;
  float mk = msk[b*Ln+i];
  size_t base = ((size_t)(b*Ln+i))*Hn;
  float v[3];
#pragma unroll
  for(int k=0;k<3;k++){
    float x = ctx[base + t + 256*k] * mk;
    v[k]=x;
    dst[base + t + 256*k] = x;
  }
  __shared__ float red4[4];
  __shared__ float redW[64];
  float ss = v[0]*v[0]+v[1]*v[1]+v[2]*v[2];
  float sst = wred_sum(ss);
  if(l==0) red4[w]=sst;
  __syncthreads();
  if(t==0) nD[b*Ln+i] = sqrtf(fmaxf(red4[0]+red4[1]+red4[2]+red4[3],0.f));
  for(int X=0;X<5;++X){
    float acc[16];
#pragma unroll
    for(int p=0;p<16;p++) acc[p]=0.f;
#pragma unroll
    for(int k=0;k<3;k++){
      int h = t+256*k;
      float vv = v[k]*v[k];
      const float4* wq = (const float4*)(W2T + ((size_t)X*Hn + h)*Pn);
      float4 q0=wq[0],q1=wq[1],q2=wq[2],q3=wq[3];
      float wv[16]={q0.x,q0.y,q0.z,q0.w,q1.x,q1.y,q1.z,q1.w,
                    q2.x,q2.y,q2.z,q2.w,q3.x,q3.y,q3.z,q3.w};
#pragma unroll
      for(int p=0;p<16;p++) acc[p]=fmaf(wv[p],vv,acc[p]);
    }
    __syncthreads();
#pragma unroll
    for(int p=0;p<16;p++){
      float a = wred_sum(acc[p]);
      if(l==0) redW[w*16+p]=a;
    }
    __syncthreads();
    if(t<16){
      float s = redW[t]+redW[16+t]+redW[32+t]+redW[48+t];
      wn[wnIdx(side,X,b,t,i)] = s;
    }
    __syncthreads();
  }
}

// ---------------- k_mm v6: W2 via vector-broadcast global loads; fused cos ----------------
// grid (Bn, Ln/4), 512 threads = (j:128, ph:2, ih:2). XCD = b.
__global__ __launch_bounds__(512, 2) void k_mm(
    const float* __restrict__ c1f, const float* __restrict__ c2f,
    const float* __restrict__ W2mp, const float* __restrict__ WN,
    const float* __restrict__ n1, const float* __restrict__ n2,
    const float* __restrict__ m1, const float* __restrict__ m2,
    const int* __restrict__ lens,
    float* __restrict__ cosM,
    float* __restrict__ mvmax, float* __restrict__ mvmean,
    float* __restrict__ part){
  const int b = blockIdx.x;
  const int i0 = blockIdx.y*4;
  const int t = threadIdx.x;
  // NOTE: no readfirstlane — ph/ih stay divergence-typed so W2 loads remain
  // VECTOR loads (64 identical lane addresses coalesce to one line, broadcast).
  const int j = t&127, ph = (t>>7)&1, ih = t>>8;

  __shared__ float sA[4*Hn];            // 12 KB
  __shared__ float sMX[Pn][Ln];         // 8 KB  side1 max exchange [p][j]
  __shared__ float sSM[Pn][Ln];         // 8 KB  side1 sum exchange [p][j]
  __shared__ float redR[8][2][8][2];    // 1 KB  side0 per-wave partials

  for(int idx=t; idx<4*Hn; idx+=512) sA[idx] = c1f[((size_t)(b*Ln+i0))*Hn + idx];
  __syncthreads();

  const int iA = i0 + 2*ih, iB = iA+1;
  const float4* brow = (const float4*)(c2f + ((size_t)(b*Ln+j))*Hn);
  const float4* aR0 = (const float4*)(sA + (2*ih  )*Hn);
  const float4* aR1 = (const float4*)(sA + (2*ih+1)*Hn);
  const float4* w2q = ((const float4*)W2mp) + ph*2;   // per h: w2q[h*4], w2q[h*4+1]

  float acc0[8], acc1[8];
#pragma unroll
  for(int pp=0;pp<8;pp++){ acc0[pp]=0.f; acc1[pp]=0.f; }
  float dot0=0.f, dot1=0.f;

  // software pipeline: rotating brow float4 pair, 8 h of compute per stage
  float4 pf0 = brow[0], pf1 = brow[1];
#pragma unroll 2
  for(int hq=0; hq<Hn/4; hq+=2){
    float4 cur0 = pf0, cur1 = pf1;
    pf0 = brow[hq+2]; pf1 = brow[hq+3];   // tail over-read stays in-workspace
    float4 a00 = aR0[hq], a01 = aR0[hq+1];
    float4 a10 = aR1[hq], a11 = aR1[hq+1];
#pragma unroll
    for(int u=0; u<2; ++u){
      float4 bq = u? cur1 : cur0;
      float4 a0 = u? a01 : a00;
      float4 a1 = u? a11 : a10;
#pragma unroll
      for(int d=0; d<4; ++d){
        int h = (hq+u)*4+d;
        float bv  = (d==0)? bq.x : (d==1)? bq.y : (d==2)? bq.z : bq.w;
        float a0v = (d==0)? a0.x : (d==1)? a0.y : (d==2)? a0.z : a0.w;
        float a1v = (d==0)? a1.x : (d==1)? a1.y : (d==2)? a1.z : a1.w;
        float4 wA = w2q[h*4], wB = w2q[h*4+1];   // vector-broadcast loads
        float pr0 = a0v*bv, pr1 = a1v*bv;
        dot0 += pr0; dot1 += pr1;
        float wv[8]={wA.x,wA.y,wA.z,wA.w,wB.x,wB.y,wB.z,wB.w};
#pragma unroll
        for(int pp=0;pp<8;pp++){
          acc0[pp]=fmaf(wv[pp],pr0,acc0[pp]);
          acc1[pp]=fmaf(wv[pp],pr1,acc1[pp]);
        }
      }
    }
  }

  // ---- fused cosine writes (ph==0 lanes own rows iA,iB at col j) ----
  if(ph==0){
    float nj = fmaxf(n2[b*Ln+j], EPSF);
    cosM[((size_t)(b*Ln+iA))*Ln + j] = dot0/(fmaxf(n1[b*Ln+iA],EPSF)*nj);
    cosM[((size_t)(b*Ln+iB))*Ln + j] = dot1/(fmaxf(n1[b*Ln+iB],EPSF)*nj);
  }

  // ---- normalize e in place ----
#pragma unroll
  for(int pp=0;pp<8;pp++){
    float sl  = sqrtf(fmaxf(WN[wnIdx(1,2,b,ph*8+pp,j)],0.f));
    float srA = sqrtf(fmaxf(WN[wnIdx(0,2,b,ph*8+pp,iA)],0.f));
    float srB = sqrtf(fmaxf(WN[wnIdx(0,2,b,ph*8+pp,iB)],0.f));
    acc0[pp] = acc0[pp]/fmaxf(srA*sl,EPSF);
    acc1[pp] = acc1[pp]/fmaxf(srB*sl,EPSF);
  }

  // ---- side1 partials (reduce over this block's 4 rows; ih-halves merge via LDS) ----
  {
    float mrA = m1[b*Ln+iA], mrB = m1[b*Ln+iB];
    float pmax[8], psum[8];
#pragma unroll
    for(int pp=0;pp<8;pp++){
      float mx=NINF, sm=0.f;
      if(mrA!=0.f){ mx=acc0[pp]; sm=acc0[pp]; }
      if(mrB!=0.f){ mx=fmaxf(mx,acc1[pp]); sm+=acc1[pp]; }
      pmax[pp]=mx; psum[pp]=sm;
    }
    if(ih==1){
#pragma unroll
      for(int pp=0;pp<8;pp++){ sMX[ph*8+pp][j]=pmax[pp]; sSM[ph*8+pp][j]=psum[pp]; }
    }
    __syncthreads();
    if(ih==0){
#pragma unroll
      for(int pp=0;pp<8;pp++){
        int p = ph*8+pp;
        float M = fmaxf(sMX[p][j], pmax[pp]);
        float S = sSM[p][j] + psum[pp];
        size_t o = ((((size_t)(b*Ln+j))*Pn + p)*32 + blockIdx.y)*2;
        part[o]=M; part[o+1]=S;
      }
    }
  }

  // ---- side0: reduce over j (mask2) ----
  {
    const bool valid = (m2[b*Ln+j]!=0.f);
    const int wv = t>>6, l = t&63;
#pragma unroll
    for(int r=0;r<2;r++){
#pragma unroll
      for(int pp=0;pp<8;pp++){
        float m = r? acc1[pp] : acc0[pp];
        float vmax = valid? m : NINF;
        float vsum = valid? m : 0.f;
        vmax = wred_max(vmax);
        vsum = wred_sum(vsum);
        if(l==0){ redR[wv][r][pp][0]=vmax; redR[wv][r][pp][1]=vsum; }
      }
    }
    __syncthreads();
    if(t<128){
      int st=t&1, pp=(t>>1)&7, r=(t>>4)&1, phh=(t>>5)&1, ihh=t>>6;
      int wbase = 4*ihh + 2*phh;
      float A = redR[wbase][r][pp][st], Bv = redR[wbase+1][r][pp][st];
      int iL = 2*ihh + r, p = phh*8+pp;
      int len2 = min(max(lens[8+b],1),Ln);
      size_t o = ((size_t)(b*Ln + i0 + iL))*Pn + p;      // side 0
      if(st==0) mvmax[o] = fmaxf(A,Bv);
      else      mvmean[o] = (A+Bv)/(float)len2;
    }
  }
}

// ---------------- k_fin: attention + all 102 features; p-in-lane Phase B ----------------
// grid (16, Ln/2): x = side*8+b → XCD = b.  side1 mv combine folded in (wave 2).
__global__ __launch_bounds__(256) void k_fin(
    const float* __restrict__ c1f, const float* __restrict__ c2f,
    const float* __restrict__ cosM,
    const float* __restrict__ n1, const float* __restrict__ n2,
    const float* __restrict__ wn, const float* __restrict__ W2T,
    const float* __restrict__ mvmax, const float* __restrict__ mvmean,
    const float* __restrict__ part,
    const int* __restrict__ lens,
    const float* __restrict__ m1, const float* __restrict__ m2,
    float* __restrict__ out){
  const int x = blockIdx.x, side = x>>3, b = x&7;
  const int r0 = blockIdx.y*2;
  const int t = threadIdx.x, w = t>>6, l = t&63;
  const float* selfF  = side? c2f : c1f;
  const float* otherF = side? c1f : c2f;
  const float* nSelf  = side? n2 : n1;
  const float* nOther = side? n1 : n2;
  const float* mInner = side? m1 : m2;
  const float* mSelfm = side? m2 : m1;
  int lenI = side? lens[b]    : lens[8+b];
  int lpO  = side? lens[16+b] : lens[24+b];
  lenI = min(max(lenI,1),Ln);
  lpO  = min(max(lpO,0),Ln-1);

  __shared__ float cS[2*Ln];
  __shared__ float mS[Ln];
  __shared__ float sV1[2][Hn];
  __shared__ float sF[Hn], sB[Hn];
  __shared__ float sAS[2][Hn], sAM[2][Hn];
  __shared__ float red[8][4];

  // ---- stage ----
  {
    if(side==0){
      const float* crow = cosM + ((size_t)(b*Ln+r0))*Ln;
      for(int idx=t; idx<2*Ln; idx+=256) cS[idx]=crow[idx];
    } else {
      int jj = t&127, rp = t>>7;   // transposed read: cos^T[r][j] = cosM[j][r]
      cS[rp*Ln+jj] = cosM[((size_t)(b*Ln+jj))*Ln + r0+rp];
    }
    if(t<Ln) mS[t]=mInner[b*Ln+t];
    const float4* s4 = (const float4*)(selfF + ((size_t)(b*Ln+r0))*Hn);
    float4* d4 = (float4*)sV1;
    for(int idx=t; idx<2*Hn/4; idx+=256) d4[idx]=s4[idx];
    const float4* f4 = (const float4*)(otherF + ((size_t)(b*Ln+lpO))*Hn);
    const float4* b4 = (const float4*)(otherF + ((size_t)(b*Ln))*Hn);
    if(t<Hn/4){ ((float4*)sF)[t]=f4[t]; ((float4*)sB)[t]=b4[t]; }
  }
  __syncthreads();

  // ---- attention accumulation (2 rows, h = 3t..3t+2) ----
  float aS0[3]={0,0,0}, aS1[3]={0,0,0}, aM0[3]={NINF,NINF,NINF}, aM1[3]={NINF,NINF,NINF};
  {
    const float* src = otherF + (size_t)b*Ln*Hn;
#pragma unroll 4
    for(int jj=0; jj<Ln; ++jj){
      float3 vk = ((const float3*)(src + (size_t)jj*Hn))[t];
      float msk = mS[jj];
      float c0=cS[jj], c1v=cS[Ln+jj];
      aS0[0]=fmaf(vk.x,c0 ,aS0[0]); aS0[1]=fmaf(vk.y,c0 ,aS0[1]); aS0[2]=fmaf(vk.z,c0 ,aS0[2]);
      aS1[0]=fmaf(vk.x,c1v,aS1[0]); aS1[1]=fmaf(vk.y,c1v,aS1[1]); aS1[2]=fmaf(vk.z,c1v,aS1[2]);
      if(msk!=0.f){
        aM0[0]=fmaxf(aM0[0],vk.x*c0 ); aM0[1]=fmaxf(aM0[1],vk.y*c0 ); aM0[2]=fmaxf(aM0[2],vk.z*c0 );
        aM1[0]=fmaxf(aM1[0],vk.x*c1v); aM1[1]=fmaxf(aM1[1],vk.y*c1v); aM1[2]=fmaxf(aM1[2],vk.z*c1v);
      }
    }
  }

  // ---- softmax over h (2 rows); -1e30 masking => fully-masked rows → uniform ----
  {
    float lm0 = fmaxf(fmaxf(aS0[0],aS0[1]),aS0[2]);
    float lm1 = fmaxf(fmaxf(aS1[0],aS1[1]),aS1[2]);
    lm0 = wred_max(lm0); lm1 = wred_max(lm1);
    if(l==0){ red[0][w]=lm0; red[1][w]=lm1; }
  }
  __syncthreads();
  float bm0 = fmaxf(fmaxf(red[0][0],red[0][1]),fmaxf(red[0][2],red[0][3]));
  float bm1 = fmaxf(fmaxf(red[1][0],red[1][1]),fmaxf(red[1][2],red[1][3]));
  __syncthreads();
  float ev0[3], ev1[3];
  {
    float es0=0.f, es1=0.f;
#pragma unroll
    for(int k=0;k<3;k++){
      ev0[k]=expf(aS0[k]-bm0); es0+=ev0[k];
      ev1[k]=expf(aS1[k]-bm1); es1+=ev1[k];
    }
    es0 = wred_sum(es0); es1 = wred_sum(es1);
    if(l==0){ red[0][w]=es0; red[1][w]=es1; }
  }
  __syncthreads();
  {
    float smr0 = mSelfm[b*Ln+r0], smr1 = mSelfm[b*Ln+r0+1];
    float bs0 = red[0][0]+red[0][1]+red[0][2]+red[0][3];
    float bs1 = red[1][0]+red[1][1]+red[1][2]+red[1][3];
    float inv0 = 1.f/fmaxf(bs0,EPSF), inv1 = 1.f/fmaxf(bs1,EPSF);
    const float u = 1.f/(float)Hn;
#pragma unroll
    for(int k=0;k<3;k++){
      sAS[0][3*t+k] = (smr0!=0.f)? ev0[k]*inv0 : u;
      sAS[1][3*t+k] = (smr1!=0.f)? ev1[k]*inv1 : u;
      sAM[0][3*t+k] = aM0[k];
      sAM[1][3*t+k] = aM1[k];
    }
  }
  __syncthreads();

  // ---- Phase A (waves 0-1) + Phase C (wave 2): independent, no barrier ----
  if(w<2){
    int rr = w;
    float cmx=NINF, csm=0.f;
    float ca = cS[rr*Ln + l], cb = cS[rr*Ln + l + 64];
    if(mS[l]!=0.f){ cmx=ca; csm=ca; }
    if(mS[l+64]!=0.f){ cmx=fmaxf(cmx,cb); csm+=cb; }
    cmx = wred_max(cmx); csm = wred_sum(csm);
    if(l==0){
      float* op = out + ((size_t)((b*2+side)*Ln + r0+rr))*Dn;
      op[0] = cmx;
      op[1] = csm/(float)lenI;
    }
  } else if(w==2){
    int rr = l>>5, qq = l&31, p = qq&15, half = qq>>4;
    float* op = out + ((size_t)((b*2+side)*Ln + r0+rr))*Dn;
    if(side==0){
      size_t o = ((size_t)(b*Ln + r0+rr))*Pn + p;
      if(half==0) op[36+p] = mvmax[o];
      else        op[52+p] = mvmean[o];
    } else {
      // combine side1 partials for row j=r0+rr, perspective p (two lanes split 32 tiles)
      const float4* p4 = (const float4*)(part +
          ((((size_t)(b*Ln + r0+rr))*Pn + p)*32 + half*16)*2);
      float mx=NINF, sm=0.f;
#pragma unroll
      for(int k=0;k<8;k++){
        float4 v = p4[k];
        mx = fmaxf(mx, fmaxf(v.x, v.z));
        sm += v.y + v.w;
      }
      mx = fmaxf(mx, __shfl_xor(mx,16));
      sm += __shfl_xor(sm,16);
      if(half==0){
        op[36+p] = mx;
        op[52+p] = sm/(float)lenI;   // lenI == lens[b] (len1) for side==1
      }
    }
  }

  // ---- Phase B: wave w handles mi=w for both rows; lane = (p, hq) ----
  {
    const int Xids[4] = {0,1,3,4};
    const int offS[4] = {2,19,68,85};
    const int X = Xids[w], offs = offS[w];
    const bool dyn = (w>=2);
    const int p = l&15, hq = l>>4;
    const int h0 = hq*192;
    const float* w2p = W2T + ((size_t)X*Hn)*Pn + p;
    float acc0=0.f, acc1=0.f, s00=0.f, s01=0.f;
    float sn0=0.f, sn1=0.f, sna0=0.f, sna1=0.f;
    if(!dyn){
      const float* bvp = (w==0)? sF : sB;
#pragma unroll 4
      for(int hh=0; hh<192; ++hh){
        int h = h0+hh;
        float w2v = w2p[(size_t)h*Pn];
        float bv = bvp[h];
        float pr0 = sV1[0][h]*bv, pr1 = sV1[1][h]*bv;
        acc0 = fmaf(w2v,pr0,acc0); acc1 = fmaf(w2v,pr1,acc1);
        s00 += pr0; s01 += pr1;
      }
    } else {
      const float* bv0p = (w==2)? sAS[0] : sAM[0];
      const float* bv1p = (w==2)? sAS[1] : sAM[1];
#pragma unroll 4
      for(int hh=0; hh<192; ++hh){
        int h = h0+hh;
        float w2v = w2p[(size_t)h*Pn];
        float bv0 = bv0p[h], bv1 = bv1p[h];
        float pr0 = sV1[0][h]*bv0, pr1 = sV1[1][h]*bv1;
        float bb0 = bv0*bv0, bb1 = bv1*bv1;
        acc0 = fmaf(w2v,pr0,acc0); acc1 = fmaf(w2v,pr1,acc1);
        sna0 = fmaf(w2v,bb0,sna0); sna1 = fmaf(w2v,bb1,sna1);
        s00 += pr0; s01 += pr1;
        sn0 += bb0; sn1 += bb1;
      }
    }
    acc0 = qred_sum(acc0); acc1 = qred_sum(acc1);
    s00  = qred_sum(s00);  s01  = qred_sum(s01);
    if(dyn){
      sna0 = qred_sum(sna0); sna1 = qred_sum(sna1);
      sn0  = qred_sum(sn0);  sn1  = qred_sum(sn1);
    }
#pragma unroll
    for(int rr=0; rr<2; ++rr){
      const int r = r0+rr;
      float accv = rr? acc1 : acc0;
      float s0v  = rr? s01  : s00;
      float snav = rr? sna1 : sna0;
      float snv  = rr? sn1  : sn0;
      float* op = out + ((size_t)((b*2+side)*Ln + r))*Dn;
      if(l<16){
        float wa = fmaxf(wn[wnIdx(side,X,b,l,r)],0.f);
        float wb = dyn? fmaxf(snav,0.f)
                      : fmaxf(wn[wnIdx(1-side,X,b,l,(w==0? lpO:0))],0.f);
        float mul = accv/(fmaxf(sqrtf(wa),EPSF)*fmaxf(sqrtf(wb),EPSF));
        op[offs+1+l] = mul;
      }
      if(l==0){
        float nb = dyn? sqrtf(fmaxf(snv,0.f)) : nOther[b*Ln + (w==0? lpO : 0)];
        float nv1 = nSelf[b*Ln+r];
        op[offs] = s0v/(fmaxf(nv1,EPSF)*fmaxf(nb,EPSF));
      }
    }
  }
}

extern "C" void kernel_launch(void* const* d_in, const int* in_sizes, int n_in,
                              void* d_out, int out_size, void* d_ws, size_t ws_size,
                              hipStream_t stream) {
  const float* ctx1 = (const float*)d_in[0];
  const float* m1   = (const float*)d_in[1];
  const float* ctx2 = (const float*)d_in[2];
  const float* m2   = (const float*)d_in[3];
  const float* wff  = (const float*)d_in[4];
  const float* wfb  = (const float*)d_in[5];
  const float* wmp  = (const float*)d_in[6];
  const float* watt = (const float*)d_in[7];
  const float* wmatt= (const float*)d_in[8];
  float* out = (float*)d_out;
  float* W = (float*)d_ws;
  int* lens = (int*)(W + OFF_LENS);

  k_prep<<<dim3(8 + (5*Pn*Hn)/256), 256, 0, stream>>>(m1,m2,wff,wfb,wmp,watt,wmatt,
      W+OFF_W2T, lens);
  k_rows<<<dim3(Ln,Bn,2), 256, 0, stream>>>(ctx1,m1,ctx2,m2, W+OFF_W2T,
      W+OFF_C1F, W+OFF_C2F, W+OFF_N1, W+OFF_N2, W+OFF_WN);
  k_mm<<<dim3(Bn, Ln/4), 512, 0, stream>>>(W+OFF_C1F, W+OFF_C2F,
      W+OFF_W2T + (size_t)2*Hn*Pn, W+OFF_WN, W+OFF_N1, W+OFF_N2,
      m1, m2, lens, W+OFF_COS,
      W+OFF_MVMAX, W+OFF_MVMEAN, W+OFF_PART);
  k_fin<<<dim3(16, Ln/2), 256, 0, stream>>>(W+OFF_C1F, W+OFF_C2F, W+OFF_COS,
      W+OFF_N1, W+OFF_N2, W+OFF_WN, W+OFF_W2T, W+OFF_MVMAX, W+OFF_MVMEAN,
      W+OFF_PART, lens, m1, m2, out);
}

// Round 11
// 241.324 us; speedup vs baseline: 1.3234x; 1.3234x over previous
//
#include <hip/hip_runtime.h>

#define Bn 8
#define Ln 128
#define Hn 768
#define Pn 16
#define Dn 102
#define EPSF 1e-8f
#define NINF -1e30f

__device__ __forceinline__ float wred_sum(float v){
#pragma unroll
  for(int o=32;o>=1;o>>=1) v += __shfl_xor(v,o);
  return v;
}
__device__ __forceinline__ float wred_max(float v){
#pragma unroll
  for(int o=32;o>=1;o>>=1) v = fmaxf(v,__shfl_xor(v,o));
  return v;
}
// sum over the 4 hq-quarters in the p-in-lane layout (lane = p + 16*hq)
__device__ __forceinline__ float qred_sum(float v){
  v += __shfl_xor(v,16);
  v += __shfl_xor(v,32);
  return v;
}

// ---- workspace layout (float element offsets; total ~12.3 MB) ----
constexpr size_t SZ_MAT   = (size_t)Bn*Ln*Hn;              // 786432
constexpr size_t OFF_C1F  = 0;
constexpr size_t OFF_C2F  = OFF_C1F + SZ_MAT;
constexpr size_t OFF_COS  = OFF_C2F + SZ_MAT;              // B*L*L
constexpr size_t OFF_N1   = OFF_COS + (size_t)Bn*Ln*Ln;    // B*L
constexpr size_t OFF_N2   = OFF_N1 + (size_t)Bn*Ln;
constexpr size_t OFF_WN   = OFF_N2 + (size_t)Bn*Ln;        // 2*5*B*P*L
constexpr size_t OFF_W2T  = OFF_WN + (size_t)2*5*Bn*Pn*Ln; // 5*H*P [X][h][p]
constexpr size_t OFF_MVMAX  = OFF_W2T + (size_t)5*Hn*Pn;   // 2*B*L*P (side0 used)
constexpr size_t OFF_MVMEAN = OFF_MVMAX + (size_t)2*Bn*Ln*Pn;
constexpr size_t OFF_PART   = OFF_MVMEAN + (size_t)2*Bn*Ln*Pn; // B*L*P*32*2
constexpr size_t OFF_LENS   = OFF_PART + (size_t)Bn*Ln*Pn*32*2; // 32 ints

__device__ __forceinline__ size_t wnIdx(int side,int X,int b,int p,int i){
  return ((((size_t)side*5 + X)*Bn + b)*Pn + p)*Ln + i;
}

// ---------------- k_prep: lengths + squared-weight tables ----------------
__global__ __launch_bounds__(256) void k_prep(
    const float* __restrict__ m1, const float* __restrict__ m2,
    const float* __restrict__ wff, const float* __restrict__ wfb,
    const float* __restrict__ wmp, const float* __restrict__ watt,
    const float* __restrict__ wmatt,
    float* __restrict__ W2T, int* __restrict__ lens){
  int t = threadIdx.x;
  if(blockIdx.x < 8){
    int b = blockIdx.x;
    __shared__ int cnt[2];
    if(t<2) cnt[t]=0;
    __syncthreads();
    if(t<Ln){
      if(m1[b*Ln+t]>0.5f) atomicAdd(&cnt[0],1);
      if(m2[b*Ln+t]>0.5f) atomicAdd(&cnt[1],1);
    }
    __syncthreads();
    if(t==0){
      lens[b]=cnt[0]; lens[8+b]=cnt[1];
      lens[16+b]=max(cnt[0]-1,0); lens[24+b]=max(cnt[1]-1,0);
    }
  } else {
    int idx = (blockIdx.x-8)*256 + t;     // < 5*768*16 = 61440
    const float* srcs[5] = {wff,wfb,wmp,watt,wmatt};
    int X = idx/(Pn*Hn);
    int r = idx%(Pn*Hn);
    int h = r/Pn, p = r%Pn;
    float w = srcs[X][p*Hn+h];
    W2T[idx] = w*w;                        // layout [X][h][p]
  }
}

// ---------------- k_rows: masked rows + norms + weighted norms ----------------
__global__ __launch_bounds__(256) void k_rows(
    const float* __restrict__ ctx1, const float* __restrict__ m1,
    const float* __restrict__ ctx2, const float* __restrict__ m2,
    const float* __restrict__ W2T,
    float* __restrict__ c1f, float* __restrict__ c2f,
    float* __restrict__ n1, float* __restrict__ n2, float* __restrict__ wn){
  int i = blockIdx.x, b = blockIdx.y, side = blockIdx.z;
  const float* ctx = side? ctx2 : ctx1;
  const float* msk = side? m2 : m1;
  float* dst = side? c2f : c1f;
  float* nD  = side? n2 : n1;
  int t = threadIdx.x, w=t>>6, l=t&63;
  float mk = msk[b*Ln+i];
  size_t base = ((size_t)(b*Ln+i))*Hn;
  float v[3];
#pragma unroll
  for(int k=0;k<3;k++){
    float x = ctx[base + t + 256*k] * mk;
    v[k]=x;
    dst[base + t + 256*k] = x;
  }
  __shared__ float red4[4];
  __shared__ float redW[64];
  float ss = v[0]*v[0]+v[1]*v[1]+v[2]*v[2];
  float sst = wred_sum(ss);
  if(l==0) red4[w]=sst;
  __syncthreads();
  if(t==0) nD[b*Ln+i] = sqrtf(fmaxf(red4[0]+red4[1]+red4[2]+red4[3],0.f));
  for(int X=0;X<5;++X){
    float acc[16];
#pragma unroll
    for(int p=0;p<16;p++) acc[p]=0.f;
#pragma unroll
    for(int k=0;k<3;k++){
      int h = t+256*k;
      float vv = v[k]*v[k];
      const float4* wq = (const float4*)(W2T + ((size_t)X*Hn + h)*Pn);
      float4 q0=wq[0],q1=wq[1],q2=wq[2],q3=wq[3];
      float wv[16]={q0.x,q0.y,q0.z,q0.w,q1.x,q1.y,q1.z,q1.w,
                    q2.x,q2.y,q2.z,q2.w,q3.x,q3.y,q3.z,q3.w};
#pragma unroll
      for(int p=0;p<16;p++) acc[p]=fmaf(wv[p],vv,acc[p]);
    }
    __syncthreads();
#pragma unroll
    for(int p=0;p<16;p++){
      float a = wred_sum(acc[p]);
      if(l==0) redW[w*16+p]=a;
    }
    __syncthreads();
    if(t<16){
      float s = redW[t]+redW[16+t]+redW[32+t]+redW[48+t];
      wn[wnIdx(side,X,b,t,i)] = s;
    }
    __syncthreads();
  }
}

// ---------------- k_mm v7: s_load W2 + barrier-synced 64-h chunks ----------------
// grid (Bn, Ln/4), 512 threads = (j:128, ph:2, ih:2). XCD = b.
__global__ __launch_bounds__(512, 2) void k_mm(
    const float* __restrict__ c1f, const float* __restrict__ c2f,
    const float* __restrict__ W2mp, const float* __restrict__ WN,
    const float* __restrict__ n1, const float* __restrict__ n2,
    const float* __restrict__ m1, const float* __restrict__ m2,
    const int* __restrict__ lens,
    float* __restrict__ cosM,
    float* __restrict__ mvmax, float* __restrict__ mvmean,
    float* __restrict__ part){
  const int b = blockIdx.x;
  const int i0 = blockIdx.y*4;
  const int t = threadIdx.x;
  const int j = t&127, ph = (t>>7)&1, ih = t>>8;
  const int phu = __builtin_amdgcn_readfirstlane(ph);   // wave-uniform → SGPR
  const int ihu = __builtin_amdgcn_readfirstlane(ih);

  __shared__ float sA[4*Hn];            // 12 KB
  __shared__ float sMX[Pn][Ln];         // 8 KB  side1 max exchange [p][j]
  __shared__ float sSM[Pn][Ln];         // 8 KB  side1 sum exchange [p][j]
  __shared__ float redR[8][2][8][2];    // 1 KB  side0 per-wave partials

  for(int idx=t; idx<4*Hn; idx+=512) sA[idx] = c1f[((size_t)(b*Ln+i0))*Hn + idx];
  __syncthreads();

  const int iA = i0 + 2*ih, iB = iA+1;
  const float4* brow = (const float4*)(c2f + ((size_t)(b*Ln+j))*Hn);
  const float4* aR0 = (const float4*)(sA + (2*ihu  )*Hn);
  const float4* aR1 = (const float4*)(sA + (2*ihu+1)*Hn);
  const float* w2b = W2mp + phu*8;      // scalar (s_load) path

  float acc0[8], acc1[8];
#pragma unroll
  for(int pp=0;pp<8;pp++){ acc0[pp]=0.f; acc1[pp]=0.f; }
  float dot0=0.f, dot1=0.f;

  // software pipeline + 12 barrier-synced chunks of 64 h:
  // the barrier keeps all 8 waves inside the same 4 KB W2 window so the
  // scalar-cache stays resident (leader misses, 7 waves hit).
  float4 pf0 = brow[0], pf1 = brow[1];
  for(int c=0; c<12; ++c){
    const int hq0 = c*16;               // 16 hq (=64 h) per chunk
#pragma unroll 2
    for(int hq=hq0; hq<hq0+16; hq+=2){
      float4 cur0 = pf0, cur1 = pf1;
      pf0 = brow[hq+2]; pf1 = brow[hq+3];   // tail over-read stays in-workspace
      float4 a00 = aR0[hq], a01 = aR0[hq+1];
      float4 a10 = aR1[hq], a11 = aR1[hq+1];
#pragma unroll
      for(int u=0; u<2; ++u){
        float4 bq = u? cur1 : cur0;
        float4 a0 = u? a01 : a00;
        float4 a1 = u? a11 : a10;
#pragma unroll
        for(int d=0; d<4; ++d){
          int h = (hq+u)*4+d;
          float bv  = (d==0)? bq.x : (d==1)? bq.y : (d==2)? bq.z : bq.w;
          float a0v = (d==0)? a0.x : (d==1)? a0.y : (d==2)? a0.z : a0.w;
          float a1v = (d==0)? a1.x : (d==1)? a1.y : (d==2)? a1.z : a1.w;
          const float* wr = w2b + (size_t)h*Pn;
          float pr0 = a0v*bv, pr1 = a1v*bv;
          dot0 += pr0; dot1 += pr1;
#pragma unroll
          for(int pp=0;pp<8;pp++){
            float wv = wr[pp];
            acc0[pp]=fmaf(wv,pr0,acc0[pp]);
            acc1[pp]=fmaf(wv,pr1,acc1[pp]);
          }
        }
      }
    }
    __syncthreads();   // keep waves within the same W2 cache window
  }

  // ---- fused cosine writes (ph==0 lanes own rows iA,iB at col j) ----
  if(ph==0){
    float nj = fmaxf(n2[b*Ln+j], EPSF);
    cosM[((size_t)(b*Ln+iA))*Ln + j] = dot0/(fmaxf(n1[b*Ln+iA],EPSF)*nj);
    cosM[((size_t)(b*Ln+iB))*Ln + j] = dot1/(fmaxf(n1[b*Ln+iB],EPSF)*nj);
  }

  // ---- normalize e in place ----
#pragma unroll
  for(int pp=0;pp<8;pp++){
    float sl  = sqrtf(fmaxf(WN[wnIdx(1,2,b,phu*8+pp,j)],0.f));
    float srA = sqrtf(fmaxf(WN[wnIdx(0,2,b,phu*8+pp,iA)],0.f));
    float srB = sqrtf(fmaxf(WN[wnIdx(0,2,b,phu*8+pp,iB)],0.f));
    acc0[pp] = acc0[pp]/fmaxf(srA*sl,EPSF);
    acc1[pp] = acc1[pp]/fmaxf(srB*sl,EPSF);
  }

  // ---- side1 partials (reduce over this block's 4 rows; ih-halves merge via LDS) ----
  {
    float mrA = m1[b*Ln+iA], mrB = m1[b*Ln+iB];
    float pmax[8], psum[8];
#pragma unroll
    for(int pp=0;pp<8;pp++){
      float mx=NINF, sm=0.f;
      if(mrA!=0.f){ mx=acc0[pp]; sm=acc0[pp]; }
      if(mrB!=0.f){ mx=fmaxf(mx,acc1[pp]); sm+=acc1[pp]; }
      pmax[pp]=mx; psum[pp]=sm;
    }
    if(ih==1){
#pragma unroll
      for(int pp=0;pp<8;pp++){ sMX[phu*8+pp][j]=pmax[pp]; sSM[phu*8+pp][j]=psum[pp]; }
    }
    __syncthreads();
    if(ih==0){
#pragma unroll
      for(int pp=0;pp<8;pp++){
        int p = phu*8+pp;
        float M = fmaxf(sMX[p][j], pmax[pp]);
        float S = sSM[p][j] + psum[pp];
        size_t o = ((((size_t)(b*Ln+j))*Pn + p)*32 + blockIdx.y)*2;
        part[o]=M; part[o+1]=S;
      }
    }
  }

  // ---- side0: reduce over j (mask2) ----
  {
    const bool valid = (m2[b*Ln+j]!=0.f);
    const int wv = t>>6, l = t&63;
#pragma unroll
    for(int r=0;r<2;r++){
#pragma unroll
      for(int pp=0;pp<8;pp++){
        float m = r? acc1[pp] : acc0[pp];
        float vmax = valid? m : NINF;
        float vsum = valid? m : 0.f;
        vmax = wred_max(vmax);
        vsum = wred_sum(vsum);
        if(l==0){ redR[wv][r][pp][0]=vmax; redR[wv][r][pp][1]=vsum; }
      }
    }
    __syncthreads();
    if(t<128){
      int st=t&1, pp=(t>>1)&7, r=(t>>4)&1, phh=(t>>5)&1, ihh=t>>6;
      int wbase = 4*ihh + 2*phh;
      float A = redR[wbase][r][pp][st], Bv = redR[wbase+1][r][pp][st];
      int iL = 2*ihh + r, p = phh*8+pp;
      int len2 = min(max(lens[8+b],1),Ln);
      size_t o = ((size_t)(b*Ln + i0 + iL))*Pn + p;      // side 0
      if(st==0) mvmax[o] = fmaxf(A,Bv);
      else      mvmean[o] = (A+Bv)/(float)len2;
    }
  }
}

// ---------------- k_fin: attention + all 102 features; p-in-lane Phase B ----------------
// grid (16, Ln/2): x = side*8+b → XCD = b.  side1 mv combine folded in (wave 2).
__global__ __launch_bounds__(256) void k_fin(
    const float* __restrict__ c1f, const float* __restrict__ c2f,
    const float* __restrict__ cosM,
    const float* __restrict__ n1, const float* __restrict__ n2,
    const float* __restrict__ wn, const float* __restrict__ W2T,
    const float* __restrict__ mvmax, const float* __restrict__ mvmean,
    const float* __restrict__ part,
    const int* __restrict__ lens,
    const float* __restrict__ m1, const float* __restrict__ m2,
    float* __restrict__ out){
  const int x = blockIdx.x, side = x>>3, b = x&7;
  const int r0 = blockIdx.y*2;
  const int t = threadIdx.x, w = t>>6, l = t&63;
  const float* selfF  = side? c2f : c1f;
  const float* otherF = side? c1f : c2f;
  const float* nSelf  = side? n2 : n1;
  const float* nOther = side? n1 : n2;
  const float* mInner = side? m1 : m2;
  const float* mSelfm = side? m2 : m1;
  int lenI = side? lens[b]    : lens[8+b];
  int lpO  = side? lens[16+b] : lens[24+b];
  lenI = min(max(lenI,1),Ln);
  lpO  = min(max(lpO,0),Ln-1);

  __shared__ float cS[2*Ln];
  __shared__ float mS[Ln];
  __shared__ float sV1[2][Hn];
  __shared__ float sF[Hn], sB[Hn];
  __shared__ float sAS[2][Hn], sAM[2][Hn];
  __shared__ float red[8][4];

  // ---- stage ----
  {
    if(side==0){
      const float* crow = cosM + ((size_t)(b*Ln+r0))*Ln;
      for(int idx=t; idx<2*Ln; idx+=256) cS[idx]=crow[idx];
    } else {
      int jj = t&127, rp = t>>7;   // transposed read: cos^T[r][j] = cosM[j][r]
      cS[rp*Ln+jj] = cosM[((size_t)(b*Ln+jj))*Ln + r0+rp];
    }
    if(t<Ln) mS[t]=mInner[b*Ln+t];
    const float4* s4 = (const float4*)(selfF + ((size_t)(b*Ln+r0))*Hn);
    float4* d4 = (float4*)sV1;
    for(int idx=t; idx<2*Hn/4; idx+=256) d4[idx]=s4[idx];
    const float4* f4 = (const float4*)(otherF + ((size_t)(b*Ln+lpO))*Hn);
    const float4* b4 = (const float4*)(otherF + ((size_t)(b*Ln))*Hn);
    if(t<Hn/4){ ((float4*)sF)[t]=f4[t]; ((float4*)sB)[t]=b4[t]; }
  }
  __syncthreads();

  // ---- attention accumulation (2 rows, h = 3t..3t+2) ----
  float aS0[3]={0,0,0}, aS1[3]={0,0,0}, aM0[3]={NINF,NINF,NINF}, aM1[3]={NINF,NINF,NINF};
  {
    const float* src = otherF + (size_t)b*Ln*Hn;
#pragma unroll 4
    for(int jj=0; jj<Ln; ++jj){
      float3 vk = ((const float3*)(src + (size_t)jj*Hn))[t];
      float msk = mS[jj];
      float c0=cS[jj], c1v=cS[Ln+jj];
      aS0[0]=fmaf(vk.x,c0 ,aS0[0]); aS0[1]=fmaf(vk.y,c0 ,aS0[1]); aS0[2]=fmaf(vk.z,c0 ,aS0[2]);
      aS1[0]=fmaf(vk.x,c1v,aS1[0]); aS1[1]=fmaf(vk.y,c1v,aS1[1]); aS1[2]=fmaf(vk.z,c1v,aS1[2]);
      if(msk!=0.f){
        aM0[0]=fmaxf(aM0[0],vk.x*c0 ); aM0[1]=fmaxf(aM0[1],vk.y*c0 ); aM0[2]=fmaxf(aM0[2],vk.z*c0 );
        aM1[0]=fmaxf(aM1[0],vk.x*c1v); aM1[1]=fmaxf(aM1[1],vk.y*c1v); aM1[2]=fmaxf(aM1[2],vk.z*c1v);
      }
    }
  }

  // ---- softmax over h (2 rows); -1e30 masking => fully-masked rows → uniform ----
  {
    float lm0 = fmaxf(fmaxf(aS0[0],aS0[1]),aS0[2]);
    float lm1 = fmaxf(fmaxf(aS1[0],aS1[1]),aS1[2]);
    lm0 = wred_max(lm0); lm1 = wred_max(lm1);
    if(l==0){ red[0][w]=lm0; red[1][w]=lm1; }
  }
  __syncthreads();
  float bm0 = fmaxf(fmaxf(red[0][0],red[0][1]),fmaxf(red[0][2],red[0][3]));
  float bm1 = fmaxf(fmaxf(red[1][0],red[1][1]),fmaxf(red[1][2],red[1][3]));
  __syncthreads();
  float ev0[3], ev1[3];
  {
    float es0=0.f, es1=0.f;
#pragma unroll
    for(int k=0;k<3;k++){
      ev0[k]=expf(aS0[k]-bm0); es0+=ev0[k];
      ev1[k]=expf(aS1[k]-bm1); es1+=ev1[k];
    }
    es0 = wred_sum(es0); es1 = wred_sum(es1);
    if(l==0){ red[0][w]=es0; red[1][w]=es1; }
  }
  __syncthreads();
  {
    float smr0 = mSelfm[b*Ln+r0], smr1 = mSelfm[b*Ln+r0+1];
    float bs0 = red[0][0]+red[0][1]+red[0][2]+red[0][3];
    float bs1 = red[1][0]+red[1][1]+red[1][2]+red[1][3];
    float inv0 = 1.f/fmaxf(bs0,EPSF), inv1 = 1.f/fmaxf(bs1,EPSF);
    const float u = 1.f/(float)Hn;
#pragma unroll
    for(int k=0;k<3;k++){
      sAS[0][3*t+k] = (smr0!=0.f)? ev0[k]*inv0 : u;
      sAS[1][3*t+k] = (smr1!=0.f)? ev1[k]*inv1 : u;
      sAM[0][3*t+k] = aM0[k];
      sAM[1][3*t+k] = aM1[k];
    }
  }
  __syncthreads();

  // ---- Phase A (waves 0-1) + Phase C (wave 2): independent, no barrier ----
  if(w<2){
    int rr = w;
    float cmx=NINF, csm=0.f;
    float ca = cS[rr*Ln + l], cb = cS[rr*Ln + l + 64];
    if(mS[l]!=0.f){ cmx=ca; csm=ca; }
    if(mS[l+64]!=0.f){ cmx=fmaxf(cmx,cb); csm+=cb; }
    cmx = wred_max(cmx); csm = wred_sum(csm);
    if(l==0){
      float* op = out + ((size_t)((b*2+side)*Ln + r0+rr))*Dn;
      op[0] = cmx;
      op[1] = csm/(float)lenI;
    }
  } else if(w==2){
    int rr = l>>5, qq = l&31, p = qq&15, half = qq>>4;
    float* op = out + ((size_t)((b*2+side)*Ln + r0+rr))*Dn;
    if(side==0){
      size_t o = ((size_t)(b*Ln + r0+rr))*Pn + p;
      if(half==0) op[36+p] = mvmax[o];
      else        op[52+p] = mvmean[o];
    } else {
      // combine side1 partials for row j=r0+rr, perspective p (two lanes split 32 tiles)
      const float4* p4 = (const float4*)(part +
          ((((size_t)(b*Ln + r0+rr))*Pn + p)*32 + half*16)*2);
      float mx=NINF, sm=0.f;
#pragma unroll
      for(int k=0;k<8;k++){
        float4 v = p4[k];
        mx = fmaxf(mx, fmaxf(v.x, v.z));
        sm += v.y + v.w;
      }
      mx = fmaxf(mx, __shfl_xor(mx,16));
      sm += __shfl_xor(sm,16);
      if(half==0){
        op[36+p] = mx;
        op[52+p] = sm/(float)lenI;   // lenI == lens[b] (len1) for side==1
      }
    }
  }

  // ---- Phase B: wave w handles mi=w for both rows; lane = (p, hq) ----
  {
    const int Xids[4] = {0,1,3,4};
    const int offS[4] = {2,19,68,85};
    const int X = Xids[w], offs = offS[w];
    const bool dyn = (w>=2);
    const int p = l&15, hq = l>>4;
    const int h0 = hq*192;
    const float* w2p = W2T + ((size_t)X*Hn)*Pn + p;
    float acc0=0.f, acc1=0.f, s00=0.f, s01=0.f;
    float sn0=0.f, sn1=0.f, sna0=0.f, sna1=0.f;
    if(!dyn){
      const float* bvp = (w==0)? sF : sB;
#pragma unroll 4
      for(int hh=0; hh<192; ++hh){
        int h = h0+hh;
        float w2v = w2p[(size_t)h*Pn];
        float bv = bvp[h];
        float pr0 = sV1[0][h]*bv, pr1 = sV1[1][h]*bv;
        acc0 = fmaf(w2v,pr0,acc0); acc1 = fmaf(w2v,pr1,acc1);
        s00 += pr0; s01 += pr1;
      }
    } else {
      const float* bv0p = (w==2)? sAS[0] : sAM[0];
      const float* bv1p = (w==2)? sAS[1] : sAM[1];
#pragma unroll 4
      for(int hh=0; hh<192; ++hh){
        int h = h0+hh;
        float w2v = w2p[(size_t)h*Pn];
        float bv0 = bv0p[h], bv1 = bv1p[h];
        float pr0 = sV1[0][h]*bv0, pr1 = sV1[1][h]*bv1;
        float bb0 = bv0*bv0, bb1 = bv1*bv1;
        acc0 = fmaf(w2v,pr0,acc0); acc1 = fmaf(w2v,pr1,acc1);
        sna0 = fmaf(w2v,bb0,sna0); sna1 = fmaf(w2v,bb1,sna1);
        s00 += pr0; s01 += pr1;
        sn0 += bb0; sn1 += bb1;
      }
    }
    acc0 = qred_sum(acc0); acc1 = qred_sum(acc1);
    s00  = qred_sum(s00);  s01  = qred_sum(s01);
    if(dyn){
      sna0 = qred_sum(sna0); sna1 = qred_sum(sna1);
      sn0  = qred_sum(sn0);  sn1  = qred_sum(sn1);
    }
#pragma unroll
    for(int rr=0; rr<2; ++rr){
      const int r = r0+rr;
      float accv = rr? acc1 : acc0;
      float s0v  = rr? s01  : s00;
      float snav = rr? sna1 : sna0;
      float snv  = rr? sn1  : sn0;
      float* op = out + ((size_t)((b*2+side)*Ln + r))*Dn;
      if(l<16){
        float wa = fmaxf(wn[wnIdx(side,X,b,l,r)],0.f);
        float wb = dyn? fmaxf(snav,0.f)
                      : fmaxf(wn[wnIdx(1-side,X,b,l,(w==0? lpO:0))],0.f);
        float mul = accv/(fmaxf(sqrtf(wa),EPSF)*fmaxf(sqrtf(wb),EPSF));
        op[offs+1+l] = mul;
      }
      if(l==0){
        float nb = dyn? sqrtf(fmaxf(snv,0.f)) : nOther[b*Ln + (w==0? lpO : 0)];
        float nv1 = nSelf[b*Ln+r];
        op[offs] = s0v/(fmaxf(nv1,EPSF)*fmaxf(nb,EPSF));
      }
    }
  }
}

extern "C" void kernel_launch(void* const* d_in, const int* in_sizes, int n_in,
                              void* d_out, int out_size, void* d_ws, size_t ws_size,
                              hipStream_t stream) {
  const float* ctx1 = (const float*)d_in[0];
  const float* m1   = (const float*)d_in[1];
  const float* ctx2 = (const float*)d_in[2];
  const float* m2   = (const float*)d_in[3];
  const float* wff  = (const float*)d_in[4];
  const float* wfb  = (const float*)d_in[5];
  const float* wmp  = (const float*)d_in[6];
  const float* watt = (const float*)d_in[7];
  const float* wmatt= (const float*)d_in[8];
  float* out = (float*)d_out;
  float* W = (float*)d_ws;
  int* lens = (int*)(W + OFF_LENS);

  k_prep<<<dim3(8 + (5*Pn*Hn)/256), 256, 0, stream>>>(m1,m2,wff,wfb,wmp,watt,wmatt,
      W+OFF_W2T, lens);
  k_rows<<<dim3(Ln,Bn,2), 256, 0, stream>>>(ctx1,m1,ctx2,m2, W+OFF_W2T,
      W+OFF_C1F, W+OFF_C2F, W+OFF_N1, W+OFF_N2, W+OFF_WN);
  k_mm<<<dim3(Bn, Ln/4), 512, 0, stream>>>(W+OFF_C1F, W+OFF_C2F,
      W+OFF_W2T + (size_t)2*Hn*Pn, W+OFF_WN, W+OFF_N1, W+OFF_N2,
      m1, m2, lens, W+OFF_COS,
      W+OFF_MVMAX, W+OFF_MVMEAN, W+OFF_PART);
  k_fin<<<dim3(16, Ln/2), 256, 0, stream>>>(W+OFF_C1F, W+OFF_C2F, W+OFF_COS,
      W+OFF_N1, W+OFF_N2, W+OFF_WN, W+OFF_W2T, W+OFF_MVMAX, W+OFF_MVMEAN,
      W+OFF_PART, lens, m1, m2, out);
}